// Round 7
// baseline (103.410 us; speedup 1.0000x reference)
//
#include <hip/hip_runtime.h>
#include <hip/hip_bf16.h>
#include <stdint.h>
#include <math.h>

// MMD: N=8192 rows (4096 source + 4096 target), D=256, fp32 in, scalar fp32 out.
// result = (1/4096^2) * sum_ij s_i s_j ksum(L2_ij),  s_i = +1 (i<4096) else -1
// ksum = w + w^2 + w^4 + w^8 + w^16,  w = exp(-L2/(16 bw0))
// bw0 = [2N*sum(sq) - 2*sum_d colsum_d^2] / (N^2-N) / 4  (analytic sum(L2))
// R1: same-address fp64 atomics -> scratch + reduce kernels.
// R2: LDS bank conflicts -> XOR chunk swizzle; triangular grid.
// R3: fp8 MX K=128 MFMA; whole-K staged once.
// R5 FAILED: per-block agent fences = L2 wb/inv per block -> 84us kgemm.
// R6: split-K 4 blk/CU + packed exp2 epilogue -> 98us. R4-vs-R6 arithmetic
//     says barriers ~ offset occupancy: barrier count is the lever.
// R7: pair-tile whole-K kgemm: each block does (tr,tc0),(tr,tc0+1) sharing
//     full-K A in LDS. 1.5 barriers/tile (was 3), 3 B staged/elem (was 4),
//     prologue amortized, no sqrt decode, diag tiles read B from Ash.

#define NTOT 8192
#define DDIM 256
#define TILE 128
#define NSP 2048   // Spart entries: 64 rows x 32 pair-slots

typedef int i32x8 __attribute__((ext_vector_type(8)));
typedef int i32x4 __attribute__((ext_vector_type(4)));
typedef float f32x4 __attribute__((ext_vector_type(4)));
typedef float f32x2 __attribute__((ext_vector_type(2)));

__device__ __forceinline__ void gl_lds16(const void* g, void* l) {
  __builtin_amdgcn_global_load_lds(
      (const __attribute__((address_space(1))) void*)g,
      (__attribute__((address_space(3))) void*)l, 16, 0, 0);
}

// ---- fp32 -> fp8(e4m3) convert + per-row sq + per-block partials ----
__global__ __launch_bounds__(256) void kconv(const float* __restrict__ src,
                                             const float* __restrict__ tgt,
                                             unsigned char* __restrict__ X8,
                                             float* __restrict__ sq,
                                             float* __restrict__ colpart,   // [256][256]
                                             float* __restrict__ sqpart) {  // [256]
  int b = blockIdx.x;           // 256 blocks, 32 rows each
  int t = threadIdx.x;
  int lane = t & 63, wave = t >> 6;
  float cp0 = 0.f, cp1 = 0.f, cp2 = 0.f, cp3 = 0.f;
  float sqp = 0.f;

  #pragma unroll
  for (int it = 0; it < 8; ++it) {
    int row = b * 32 + it * 4 + wave;
    const float* base = (row < 4096) ? (src + (size_t)row * DDIM)
                                     : (tgt + (size_t)(row - 4096) * DDIM);
    float4 v = ((const float4*)base)[lane];
    int p = __builtin_amdgcn_cvt_pk_fp8_f32(v.x, v.y, 0, false);
    p = __builtin_amdgcn_cvt_pk_fp8_f32(v.z, v.w, p, true);
    ((int*)(X8 + (size_t)row * DDIM))[lane] = p;
    float f0 = __builtin_amdgcn_cvt_f32_fp8(p, 0);
    float f1 = __builtin_amdgcn_cvt_f32_fp8(p, 1);
    float f2 = __builtin_amdgcn_cvt_f32_fp8(p, 2);
    float f3 = __builtin_amdgcn_cvt_f32_fp8(p, 3);
    cp0 += f0; cp1 += f1; cp2 += f2; cp3 += f3;
    float s = f0 * f0 + f1 * f1 + f2 * f2 + f3 * f3;
    #pragma unroll
    for (int off = 32; off; off >>= 1) s += __shfl_down(s, off);
    if (lane == 0) { sq[row] = s; sqp += s; }
  }

  __shared__ float cred[4][256];
  __shared__ float sred[4];
  ((float4*)&cred[wave][lane * 4])[0] = make_float4(cp0, cp1, cp2, cp3);
  if (lane == 0) sred[wave] = sqp;
  __syncthreads();
  float csum = cred[0][t] + cred[1][t] + cred[2][t] + cred[3][t];
  colpart[b * 256 + t] = csum;
  if (t == 0) sqpart[b] = sred[0] + sred[1] + sred[2] + sred[3];
}

// ---- single-block reduce: accs[0] = sum(sq), accs[1] = sum_d colsum_d^2 ----
__global__ __launch_bounds__(256) void kred(const float* __restrict__ colpart,
                                            const float* __restrict__ sqpart,
                                            double* __restrict__ accs) {
  int t = threadIdx.x;
  float csum = 0.f;
  #pragma unroll 16
  for (int bb = 0; bb < 256; ++bb) csum += colpart[bb * 256 + t];
  __shared__ double r1[256], r2[256];
  r1[t] = (double)csum * (double)csum;
  r2[t] = (double)sqpart[t];
  __syncthreads();
  for (int off = 128; off; off >>= 1) {
    if (t < off) { r1[t] += r1[t + off]; r2[t] += r2[t + off]; }
    __syncthreads();
  }
  if (t == 0) { accs[1] = r1[0]; accs[0] = r2[0]; }
}

// ---- main: pair-tile whole-K Gram (MX-fp8), full-A LDS reuse ----
__global__ __launch_bounds__(256, 2) void kgemm(const unsigned char* __restrict__ X8,
                                                const float* __restrict__ sq,
                                                const double* __restrict__ accs,
                                                double* __restrict__ Spart) {
  int tr = blockIdx.y;          // tile row 0..63
  int p  = blockIdx.x;          // pair slot 0..31
  int tc0 = tr + 2 * p;
  int bid = tr * 32 + p;
  int t = threadIdx.x;
  if (tc0 > 63) {               // dead pair slot: ws is poisoned, write clean 0
    if (t == 0) Spart[bid] = 0.0;
    return;
  }
  int tc1 = tc0 + 1;            // may be 64 (absent)

  __shared__ alignas(16) unsigned char Ash[TILE * DDIM];  // 32 KB, full K
  __shared__ alignas(16) unsigned char Bsh[TILE * DDIM];  // 32 KB, full K
  __shared__ float sqR2[TILE], sqC0[TILE], sqC1[TILE];
  __shared__ double red[4];

  double ssq = accs[0], scol = accs[1];
  double sumL2 = 2.0 * 8192.0 * ssq - 2.0 * scol;
  double bw0 = sumL2 / (8192.0 * 8192.0 - 8192.0) / 4.0;
  float kk = (float)(-1.44269504088896 / (16.0 * bw0));  // cs * log2(e)

  const unsigned char* Ag = X8 + (size_t)tr * TILE * DDIM;

  if (t < 128) {
    sqR2[t] = kk * sq[tr * TILE + t];
    if (tc1 <= 63) sqC1[t] = kk * sq[tc1 * TILE + t];
  } else {
    sqC0[t - 128] = kk * sq[tc0 * TILE + (t - 128)];
  }

  // stage full-K A (2048 chunks, 8/thread); slot c = row*16 + (kc ^ (row&15))
  #pragma unroll
  for (int cc = 0; cc < 8; ++cc) {
    int c = t + cc * 256;
    int row = c >> 4, kcs = c & 15;
    int kc = kcs ^ (row & 15);
    gl_lds16(Ag + (size_t)row * DDIM + kc * 16, Ash + c * 16);
  }
  bool diag0 = (tc0 == tr);
  if (!diag0) {
    const unsigned char* Bg = X8 + (size_t)tc0 * TILE * DDIM;
    #pragma unroll
    for (int cc = 0; cc < 8; ++cc) {
      int c = t + cc * 256;
      int row = c >> 4, kcs = c & 15;
      int kc = kcs ^ (row & 15);
      gl_lds16(Bg + (size_t)row * DDIM + kc * 16, Bsh + c * 16);
    }
  }
  __syncthreads();

  int wave = t >> 6, lane = t & 63;
  int mrow = lane & 15, q = lane >> 4;
  int wr = (wave & 1) * 64, wc = (wave >> 1) * 64;
  const int sone = 0x7F7F7F7F;  // e8m0 scale = 1.0
  float a2s = -2.f * kk;
  f32x2 a2 = {a2s, a2s};
  int rq = q * 4, cl = mrow;
  double dsd = 0.0;

  #pragma unroll
  for (int tile = 0; tile < 2; ++tile) {
    int tc = tile ? tc1 : tc0;
    if (tile && tc1 > 63) break;
    const unsigned char* Bs = (tile == 0 && diag0) ? Ash : Bsh;
    const float* sqC2 = tile ? sqC1 : sqC0;

    f32x4 acc[4][4];
    #pragma unroll
    for (int i = 0; i < 4; ++i)
      #pragma unroll
      for (int j = 0; j < 4; ++j) acc[i][j] = (f32x4){0.f, 0.f, 0.f, 0.f};

    #pragma unroll
    for (int ki = 0; ki < 2; ++ki) {
      int kc0 = ki * 8 + q * 2;
      i32x8 af[4], bf[4];
      #pragma unroll
      for (int f = 0; f < 4; ++f) {
        int rowA = wr + 16 * f + mrow;
        int rowB = wc + 16 * f + mrow;
        *(i32x4*)&af[f]       = *(const i32x4*)&Ash[rowA * DDIM + (kc0 ^ mrow) * 16];
        *((i32x4*)&af[f] + 1) = *(const i32x4*)&Ash[rowA * DDIM + ((kc0 + 1) ^ mrow) * 16];
        *(i32x4*)&bf[f]       = *(const i32x4*)&Bs[rowB * DDIM + (kc0 ^ mrow) * 16];
        *((i32x4*)&bf[f] + 1) = *(const i32x4*)&Bs[rowB * DDIM + ((kc0 + 1) ^ mrow) * 16];
      }
      #pragma unroll
      for (int fr = 0; fr < 4; ++fr)
        #pragma unroll
        for (int fc = 0; fc < 4; ++fc)
          acc[fr][fc] = __builtin_amdgcn_mfma_scale_f32_16x16x128_f8f6f4(
              af[fr], bf[fc], acc[fr][fc], 0, 0, 0, sone, 0, sone);
    }

    // epilogue: x = -2k*dot + sr + sc; w = exp2(x); ksum = w+w2+w4+w8+w16.
    // C/D layout col=lane&15, row=(lane>>4)*4+reg [m89/m91; dtype-indep]
    f32x2 sum2 = {0.f, 0.f};
    #pragma unroll
    for (int fr = 0; fr < 4; ++fr) {
      int rbase = wr + 16 * fr + rq;
      f32x2 sr01 = {sqR2[rbase + 0], sqR2[rbase + 1]};
      f32x2 sr23 = {sqR2[rbase + 2], sqR2[rbase + 3]};
      #pragma unroll
      for (int fc = 0; fc < 4; ++fc) {
        float sc = sqC2[wc + 16 * fc + cl];
        f32x2 scv = {sc, sc};
        f32x2 d01 = {acc[fr][fc][0], acc[fr][fc][1]};
        f32x2 d23 = {acc[fr][fc][2], acc[fr][fc][3]};
        f32x2 x01 = a2 * d01 + (sr01 + scv);
        f32x2 x23 = a2 * d23 + (sr23 + scv);
        f32x2 w01 = {__builtin_amdgcn_exp2f(x01.x), __builtin_amdgcn_exp2f(x01.y)};
        f32x2 w23 = {__builtin_amdgcn_exp2f(x23.x), __builtin_amdgcn_exp2f(x23.y)};
        f32x2 p01 = w01 * w01, p23 = w23 * w23;           // w^2
        f32x2 s01 = w01 + p01, s23 = w23 + p23;
        p01 = p01 * p01; p23 = p23 * p23;                 // w^4
        s01 = s01 + p01; s23 = s23 + p23;
        p01 = p01 * p01; p23 = p23 * p23;                 // w^8
        s01 = s01 + p01; s23 = s23 + p23;
        p01 = p01 * p01; p23 = p23 * p23;                 // w^16
        s01 = s01 + p01; s23 = s23 + p23;
        sum2 = sum2 + (s01 + s23);
      }
    }
    float lsum = sum2.x + sum2.y;
    double wt = (tc == tr) ? 1.0 : 2.0;
    if ((tr < 32) != (tc < 32)) wt = -wt;  // s_i*s_j uniform per 128-tile
    dsd += (double)lsum * wt;

    // restage B for tile 1 (never diagonal: tc1 > tr always)
    if (tile == 0 && tc1 <= 63) {
      __syncthreads();  // all Bsh reads of tile 0 complete
      const unsigned char* Bg = X8 + (size_t)tc1 * TILE * DDIM;
      #pragma unroll
      for (int cc = 0; cc < 8; ++cc) {
        int c = t + cc * 256;
        int row = c >> 4, kcs = c & 15;
        int kc = kcs ^ (row & 15);
        gl_lds16(Bg + (size_t)row * DDIM + kc * 16, Bsh + c * 16);
      }
      __syncthreads();
    }
  }

  #pragma unroll
  for (int off = 32; off; off >>= 1) dsd += __shfl_down(dsd, off);
  if (lane == 0) red[wave] = dsd;
  __syncthreads();
  if (t == 0) Spart[bid] = red[0] + red[1] + red[2] + red[3];
}

// ---- final reduce of 2048 per-block partials ----
__global__ __launch_bounds__(256) void kfin(const double* __restrict__ Spart,
                                            float* __restrict__ out) {
  int t = threadIdx.x;
  double s = 0.0;
  #pragma unroll
  for (int i = 0; i < 8; ++i) s += Spart[t + i * 256];
  __shared__ double red[256];
  red[t] = s;
  __syncthreads();
  for (int off = 128; off; off >>= 1) {
    if (t < off) red[t] += red[t + off];
    __syncthreads();
  }
  if (t == 0) out[0] = (float)(red[0] / (4096.0 * 4096.0));
}

extern "C" void kernel_launch(void* const* d_in, const int* in_sizes, int n_in,
                              void* d_out, int out_size, void* d_ws, size_t ws_size,
                              hipStream_t stream) {
  const float* src = (const float*)d_in[0];
  const float* tgt = (const float*)d_in[1];
  char* ws = (char*)d_ws;
  unsigned char* X8 = (unsigned char*)ws;             // 8192*256 = 2 MiB
  float* sq      = (float*)(ws + 2097152);            // 32 KiB
  float* colpart = (float*)(ws + 2129920);            // 256 KiB
  float* sqpart  = (float*)(ws + 2392064);            // 1 KiB
  double* accs   = (double*)(ws + 2393088);           // 16 B
  double* Spart  = (double*)(ws + 2393104);           // 16 KiB
  float* out = (float*)d_out;

  hipLaunchKernelGGL(kconv, dim3(256), dim3(256), 0, stream, src, tgt, X8, sq, colpart, sqpart);
  hipLaunchKernelGGL(kred, dim3(1), dim3(256), 0, stream, colpart, sqpart, accs);
  hipLaunchKernelGGL(kgemm, dim3(32, 64), dim3(256), 0, stream, X8, sq, accs, Spart);
  hipLaunchKernelGGL(kfin, dim3(1), dim3(256), 0, stream, Spart, out);
}

// Round 8
// 94.528 us; speedup vs baseline: 1.0940x; 1.0940x over previous
//
#include <hip/hip_runtime.h>
#include <hip/hip_bf16.h>
#include <stdint.h>
#include <math.h>

// MMD: N=8192 rows (4096 source + 4096 target), D=256, fp32 in, scalar fp32 out.
// result = (1/4096^2) * sum_ij s_i s_j ksum(L2_ij),  s_i = +1 (i<4096) else -1
// ksum = w + w^2 + w^4 + w^8 + w^16,  w = exp(-L2/(16 bw0))
// bw0 = [2N*sum(sq) - 2*sum_d colsum_d^2] / (N^2-N) / 4  (analytic sum(L2))
// R1: same-address fp64 CAS atomics catastrophic -> avoid.
// R2: LDS bank conflicts -> XOR chunk swizzle.
// R3: fp8 MX K=128 MFMA.
// R5 FAILED: per-block agent fences (L2 wb/inv) -> 84us. Avoid fences.
// R6 (best, 98us): split-K halves, 34KB LDS -> 4 blk/CU, packed exp2 epilogue.
// R7 FAILED: pair-tile whole-K -> 2 blk/CU -> 103us. Occupancy > barriers >
//     staged bytes. 92 VGPR caps at 4 waves/SIMD; R6 is the occupancy max.
// R8: R6 kgemm verbatim + (a) kred eliminated: kconv does native-f32
//     distinct-address atomics into colsum[256]+ssq; kgemm computes bw0
//     wave-redundantly in prologue, hidden behind half-0 staging issue;
//     (b) diagonal tiles dispatched last (light tail round); (c) 1KB memset
//     node replaces the kred kernel+gap.

#define NTOT 8192
#define DDIM 256
#define TILE 128
#define NBLK 2080   // 2016 strict-upper off-diag + 64 diagonal (last)

typedef int i32x8 __attribute__((ext_vector_type(8)));
typedef int i32x4 __attribute__((ext_vector_type(4)));
typedef float f32x4 __attribute__((ext_vector_type(4)));
typedef float f32x2 __attribute__((ext_vector_type(2)));

__device__ __forceinline__ void gl_lds16(const void* g, void* l) {
  __builtin_amdgcn_global_load_lds(
      (const __attribute__((address_space(1))) void*)g,
      (__attribute__((address_space(3))) void*)l, 16, 0, 0);
}

// ---- fp32 -> fp8(e4m3) convert + per-row sq + f32-atomic column/sq sums ----
__global__ __launch_bounds__(256) void kconv(const float* __restrict__ src,
                                             const float* __restrict__ tgt,
                                             unsigned char* __restrict__ X8,
                                             float* __restrict__ sq,
                                             float* __restrict__ colsum,   // [256] (+[256]=ssq)
                                             float* __restrict__ ssqacc) {
  int b = blockIdx.x;           // 256 blocks, 32 rows each
  int t = threadIdx.x;
  int lane = t & 63, wave = t >> 6;
  float cp0 = 0.f, cp1 = 0.f, cp2 = 0.f, cp3 = 0.f;
  float sqp = 0.f;

  #pragma unroll
  for (int it = 0; it < 8; ++it) {
    int row = b * 32 + it * 4 + wave;
    const float* base = (row < 4096) ? (src + (size_t)row * DDIM)
                                     : (tgt + (size_t)(row - 4096) * DDIM);
    float4 v = ((const float4*)base)[lane];
    int p = __builtin_amdgcn_cvt_pk_fp8_f32(v.x, v.y, 0, false);
    p = __builtin_amdgcn_cvt_pk_fp8_f32(v.z, v.w, p, true);
    ((int*)(X8 + (size_t)row * DDIM))[lane] = p;
    float f0 = __builtin_amdgcn_cvt_f32_fp8(p, 0);
    float f1 = __builtin_amdgcn_cvt_f32_fp8(p, 1);
    float f2 = __builtin_amdgcn_cvt_f32_fp8(p, 2);
    float f3 = __builtin_amdgcn_cvt_f32_fp8(p, 3);
    cp0 += f0; cp1 += f1; cp2 += f2; cp3 += f3;
    float s = f0 * f0 + f1 * f1 + f2 * f2 + f3 * f3;
    #pragma unroll
    for (int off = 32; off; off >>= 1) s += __shfl_down(s, off);
    if (lane == 0) { sq[row] = s; sqp += s; }
  }

  __shared__ float cred[4][256];
  __shared__ float sred[4];
  ((float4*)&cred[wave][lane * 4])[0] = make_float4(cp0, cp1, cp2, cp3);
  if (lane == 0) sred[wave] = sqp;
  __syncthreads();
  float csum = cred[0][t] + cred[1][t] + cred[2][t] + cred[3][t];
  // native f32 atomics: 256 distinct addresses (no CAS, no contention hot-spot)
  atomicAdd(&colsum[t], csum);
  if (t == 0) atomicAdd(ssqacc, sred[0] + sred[1] + sred[2] + sred[3]);
}

// ---- main: triangular Gram, MX-fp8 K=128 x2 halves, 34KB LDS, 4 blk/CU ----
// b < 2016: strict-upper off-diag tile; b >= 2016: diagonal tile (light, last)
__global__ __launch_bounds__(256, 4) void kgemm(const unsigned char* __restrict__ X8,
                                                const float* __restrict__ sq,
                                                const float* __restrict__ colsum,
                                                const float* __restrict__ ssqacc,
                                                double* __restrict__ Spart) {
  int b = blockIdx.x;
  int tr, tc;
  if (b < 2016) {  // strict upper: offset(tr) = tr*(127-tr)/2
    tr = (int)((127.0 - sqrt(127.0 * 127.0 - 8.0 * (double)b)) * 0.5);
    while (tr > 0 && tr * (127 - tr) / 2 > b) --tr;
    while ((tr + 1) * (126 - tr) / 2 <= b) ++tr;
    tc = tr + 1 + (b - tr * (127 - tr) / 2);
  } else {
    tr = tc = b - 2016;
  }
  bool diag = (tr == tc);

  __shared__ alignas(16) unsigned char Ash[TILE * 128];  // 16 KB (one K-half)
  __shared__ alignas(16) unsigned char Bsh[TILE * 128];  // 16 KB
  __shared__ float sqR2[TILE], sqC2[TILE];
  __shared__ double red[4];

  int t = threadIdx.x;
  int wave = t >> 6, lane = t & 63;
  int mrow = lane & 15, q = lane >> 4;
  int wr = (wave & 1) * 64, wc = (wave >> 1) * 64;
  const int sone = 0x7F7F7F7F;  // e8m0 scale = 1.0

  const unsigned char* Ag = X8 + (size_t)tr * TILE * DDIM;
  const unsigned char* Bg = X8 + (size_t)tc * TILE * DDIM;

  // ---- issue half-0 staging FIRST (bw0 compute hides behind it) ----
  #pragma unroll
  for (int cc = 0; cc < 4; ++cc) {
    int c = t + cc * 256;
    int row = c >> 3, kcs = c & 7;
    int kc = kcs ^ (row & 7);
    gl_lds16(Ag + (size_t)row * DDIM + kc * 16, Ash + c * 16);
  }
  if (!diag) {
    #pragma unroll
    for (int cc = 0; cc < 4; ++cc) {
      int c = t + cc * 256;
      int row = c >> 3, kcs = c & 7;
      int kc = kcs ^ (row & 7);
      gl_lds16(Bg + (size_t)row * DDIM + kc * 16, Bsh + c * 16);
    }
  }

  // ---- wave-redundant bw0: colsum^2 sum + ssq, 6 shuffle rounds, no LDS ----
  float4 cv = ((const float4*)colsum)[lane];
  float scp = cv.x * cv.x + cv.y * cv.y + cv.z * cv.z + cv.w * cv.w;
  #pragma unroll
  for (int off = 32; off; off >>= 1) scp += __shfl_down(scp, off);
  scp = __shfl(scp, 0);                 // Σ colsum_d^2 (all lanes)
  float ssq = *ssqacc;
  double sumL2 = 2.0 * 8192.0 * (double)ssq - 2.0 * (double)scp;
  double bw0 = sumL2 / (8192.0 * 8192.0 - 8192.0) / 4.0;
  float kk = (float)(-1.44269504088896 / (16.0 * bw0));  // cs * log2(e)

  if (t < 128) sqR2[t] = kk * sq[tr * TILE + t];
  else         sqC2[t - 128] = kk * sq[tc * TILE + (t - 128)];

  f32x4 acc[4][4];
  #pragma unroll
  for (int i = 0; i < 4; ++i)
    #pragma unroll
    for (int j = 0; j < 4; ++j) acc[i][j] = (f32x4){0.f, 0.f, 0.f, 0.f};

  // ---- two K-halves of 128 bytes, single-buffered ----
  for (int s = 0; s < 2; ++s) {
    if (s) {  // restage half 1
      __syncthreads();  // all reads of half 0 complete
      #pragma unroll
      for (int cc = 0; cc < 4; ++cc) {
        int c = t + cc * 256;
        int row = c >> 3, kcs = c & 7;
        int kc = kcs ^ (row & 7);
        gl_lds16(Ag + (size_t)row * DDIM + 128 + kc * 16, Ash + c * 16);
      }
      if (!diag) {
        #pragma unroll
        for (int cc = 0; cc < 4; ++cc) {
          int c = t + cc * 256;
          int row = c >> 3, kcs = c & 7;
          int kc = kcs ^ (row & 7);
          gl_lds16(Bg + (size_t)row * DDIM + 128 + kc * 16, Bsh + c * 16);
        }
      }
    }
    __syncthreads();  // staging done (s=0: also sqR2/sqC2 visible)

    const unsigned char* Bs = diag ? Ash : Bsh;
    int kc0 = q * 2;
    i32x8 af[4], bf[4];
    #pragma unroll
    for (int f = 0; f < 4; ++f) {
      int rowA = wr + 16 * f + mrow;
      int rowB = wc + 16 * f + mrow;
      int sw = mrow & 7;
      *(i32x4*)&af[f]       = *(const i32x4*)&Ash[rowA * 128 + (kc0 ^ sw) * 16];
      *((i32x4*)&af[f] + 1) = *(const i32x4*)&Ash[rowA * 128 + ((kc0 + 1) ^ sw) * 16];
      *(i32x4*)&bf[f]       = *(const i32x4*)&Bs[rowB * 128 + (kc0 ^ sw) * 16];
      *((i32x4*)&bf[f] + 1) = *(const i32x4*)&Bs[rowB * 128 + ((kc0 + 1) ^ sw) * 16];
    }
    #pragma unroll
    for (int fr = 0; fr < 4; ++fr)
      #pragma unroll
      for (int fc = 0; fc < 4; ++fc)
        acc[fr][fc] = __builtin_amdgcn_mfma_scale_f32_16x16x128_f8f6f4(
            af[fr], bf[fc], acc[fr][fc], 0, 0, 0, sone, 0, sone);
  }

  // epilogue: x = -2k*dot + sr + sc; w = exp2(x); ksum = w+w2+w4+w8+w16.
  // packed f32x2; no clamp (only diag ~0, err negligible).
  // C/D layout col=lane&15, row=(lane>>4)*4+reg [m89/m91; dtype-indep]
  float a2s = -2.f * kk;
  f32x2 a2 = {a2s, a2s};
  f32x2 sum2 = {0.f, 0.f};
  int rq = q * 4, cl = mrow;
  #pragma unroll
  for (int fr = 0; fr < 4; ++fr) {
    int rbase = wr + 16 * fr + rq;
    f32x2 sr01 = {sqR2[rbase + 0], sqR2[rbase + 1]};
    f32x2 sr23 = {sqR2[rbase + 2], sqR2[rbase + 3]};
    #pragma unroll
    for (int fc = 0; fc < 4; ++fc) {
      float sc = sqC2[wc + 16 * fc + cl];
      f32x2 scv = {sc, sc};
      f32x2 d01 = {acc[fr][fc][0], acc[fr][fc][1]};
      f32x2 d23 = {acc[fr][fc][2], acc[fr][fc][3]};
      f32x2 x01 = a2 * d01 + (sr01 + scv);
      f32x2 x23 = a2 * d23 + (sr23 + scv);
      f32x2 w01 = {__builtin_amdgcn_exp2f(x01.x), __builtin_amdgcn_exp2f(x01.y)};
      f32x2 w23 = {__builtin_amdgcn_exp2f(x23.x), __builtin_amdgcn_exp2f(x23.y)};
      f32x2 p01 = w01 * w01, p23 = w23 * w23;           // w^2
      f32x2 s01 = w01 + p01, s23 = w23 + p23;
      p01 = p01 * p01; p23 = p23 * p23;                 // w^4
      s01 = s01 + p01; s23 = s23 + p23;
      p01 = p01 * p01; p23 = p23 * p23;                 // w^8
      s01 = s01 + p01; s23 = s23 + p23;
      p01 = p01 * p01; p23 = p23 * p23;                 // w^16
      s01 = s01 + p01; s23 = s23 + p23;
      sum2 = sum2 + (s01 + s23);
    }
  }
  float lsum = sum2.x + sum2.y;

  double wt = diag ? 1.0 : 2.0;
  if ((tr < 32) != (tc < 32)) wt = -wt;  // s_i*s_j uniform per 128-tile
  double ds = (double)lsum * wt;
  #pragma unroll
  for (int off = 32; off; off >>= 1) ds += __shfl_down(ds, off);
  if (lane == 0) red[wave] = ds;
  __syncthreads();
  if (t == 0) Spart[b] = red[0] + red[1] + red[2] + red[3];
}

// ---- final reduce of 2080 per-block partials ----
__global__ __launch_bounds__(256) void kfin(const double* __restrict__ Spart,
                                            float* __restrict__ out) {
  int t = threadIdx.x;
  double s = 0.0;
  #pragma unroll
  for (int i = 0; i < 9; ++i) {
    int idx = t + i * 256;
    if (idx < NBLK) s += Spart[idx];
  }
  __shared__ double red[256];
  red[t] = s;
  __syncthreads();
  for (int off = 128; off; off >>= 1) {
    if (t < off) red[t] += red[t + off];
    __syncthreads();
  }
  if (t == 0) out[0] = (float)(red[0] / (4096.0 * 4096.0));
}

extern "C" void kernel_launch(void* const* d_in, const int* in_sizes, int n_in,
                              void* d_out, int out_size, void* d_ws, size_t ws_size,
                              hipStream_t stream) {
  const float* src = (const float*)d_in[0];
  const float* tgt = (const float*)d_in[1];
  char* ws = (char*)d_ws;
  unsigned char* X8 = (unsigned char*)ws;             // 8192*256 = 2 MiB
  float* sq      = (float*)(ws + 2097152);            // 32 KiB
  float* colsum  = (float*)(ws + 2129920);            // 256 f + 1 f (ssq)
  float* ssqacc  = colsum + 256;
  double* Spart  = (double*)(ws + 2131968);           // 16.25 KiB
  float* out = (float*)d_out;

  hipMemsetAsync((void*)colsum, 0, 1040, stream);     // zero atomic targets
  hipLaunchKernelGGL(kconv, dim3(256), dim3(256), 0, stream,
                     src, tgt, X8, sq, colsum, ssqacc);
  hipLaunchKernelGGL(kgemm, dim3(NBLK), dim3(256), 0, stream,
                     X8, sq, colsum, ssqacc, Spart);
  hipLaunchKernelGGL(kfin, dim3(1), dim3(256), 0, stream, Spart, out);
}